// Round 16
// baseline (194.257 us; speedup 1.0000x reference)
//
#include <hip/hip_runtime.h>

// MSDeformAttn: B=2, LQ=LV=11109, D=256, NH=8, HD=32, NL=3, NP=4
// shapes: (92,92),(46,46),(23,23); starts: 0, 8464, 10580
#define LQn   11109
#define MTOT  22218   // B * LQ

typedef __attribute__((ext_vector_type(8))) short short8;
typedef __attribute__((ext_vector_type(4))) float f32x4;

__device__ __forceinline__ unsigned short f2bf(float f) {
  union { float f; unsigned int u; } v; v.f = f;
  unsigned int r = v.u + 0x7fffu + ((v.u >> 16) & 1u);  // RNE
  return (unsigned short)(r >> 16);
}

// bijective XCD chunk swizzle: consecutive logical blocks -> same XCD
__device__ __forceinline__ int xcd_swz(int bid, int nwg) {
  const int xcd = bid & 7, pos = bid >> 3;
  const int q = nwg >> 3, r = nwg & 7;
  return (xcd < r ? xcd * (q + 1) : r * (q + 1) + (xcd - r) * q) + pos;
}

// ---------------- weight prep: transpose to (N x K) bf16, concat biases ----------------
__global__ __launch_bounds__(256) void prep_weights(
    const float* __restrict__ Wval, const float* __restrict__ Woff,
    const float* __restrict__ Wattn, const float* __restrict__ Wout,
    const float* __restrict__ boff, const float* __restrict__ battn,
    unsigned short* __restrict__ Wval_t, unsigned short* __restrict__ Wcat_t,
    unsigned short* __restrict__ Wout_t, float* __restrict__ bcat) {
  int i = blockIdx.x * 256 + threadIdx.x;   // grid = 288 blocks -> i < 73728
  int n = i >> 8, k = i & 255;              // Wt[n][k] = W[k][n]
  if (n < 256) {
    Wval_t[i] = f2bf(Wval[k * 256 + n]);
    Wout_t[i] = f2bf(Wout[k * 256 + n]);
  }
  float src = (n < 192) ? Woff[k * 192 + n] : Wattn[k * 96 + (n - 192)];
  Wcat_t[i] = f2bf(src);
  if (i < 288) bcat[i] = (i < 192) ? boff[i] : battn[i - 192];
}

// ---------------- fused GEMM1+GEMM2: 64x64 tiles, LDS double-buffer (20.5KB),
// ONE barrier per K-step, 2-deep register prefetch. 1D grid 348*9, XCD-chunk
// swizzled with bm = lb/9: the 9 blocks sharing an A panel are CONSECUTIVE ->
// same XCD -> A panel L3-fetched once, L2-hit 8x.
__global__ __launch_bounds__(256) void gemm_fused12(
    const float* __restrict__ Aval,           // (M,256) fp32
    const float* __restrict__ Aq,             // (M,256) fp32
    const unsigned short* __restrict__ Bval,  // (256,256) bf16 N-major
    const unsigned short* __restrict__ Bcat,  // (288,256) bf16 N-major
    const float* __restrict__ bval, const float* __restrict__ bcat,
    unsigned short* __restrict__ value16,     // [b][h][pix][32] bf16
    float* __restrict__ logits) {             // (M,288) fp32
  __shared__ unsigned short As[2][64][40];    // 10.24 KB
  __shared__ unsigned short Bs[2][64][40];    // 10.24 KB

  const int lb = xcd_swz(blockIdx.x, gridDim.x);
  const int bm = lb / 9;
  int bn = lb - bm * 9;
  const bool is2 = bn >= 4;
  if (is2) bn -= 4;
  const float* __restrict__ A = is2 ? Aq : Aval;
  const unsigned short* __restrict__ Bt = is2 ? Bcat : Bval;
  const float* __restrict__ bias = is2 ? bcat : bval;
  const int N = is2 ? 288 : 256;

  const int t = threadIdx.x;
  const int wave = t >> 6, lane = t & 63;
  const int wm = wave >> 1, wn = wave & 1;
  const int quad = lane >> 4, l16 = lane & 15;

  const int ldr = t >> 2;
  const int ldk = (t & 3) * 8;
  const int arow = bm * 64 + ldr;
  const int brow = bn * 64 + ldr;
  const bool aok = arow < MTOT;
  const bool bok = brow < N;
  const float* ap = A + (size_t)arow * 256 + ldk;
  const unsigned short* bp = Bt + (size_t)brow * 256 + ldk;

  f32x4 acc[2][2];
  for (int i = 0; i < 2; i++)
    for (int j = 0; j < 2; j++) acc[i][j] = (f32x4){0.f, 0.f, 0.f, 0.f};

  // prologue: kb=0 in c-regs, kb=1 in n-regs
  float4 a0c = {0.f,0.f,0.f,0.f}, a1c = a0c, a0n = a0c, a1n = a0c;
  uint4 bvc = {0u,0u,0u,0u}, bvn = bvc;
  if (aok) { a0c = *(const float4*)(ap);      a1c = *(const float4*)(ap + 4);
             a0n = *(const float4*)(ap + 32); a1n = *(const float4*)(ap + 36); }
  if (bok) { bvc = *(const uint4*)(bp);       bvn = *(const uint4*)(bp + 32); }

  {
    ushort4 lo, hi;
    lo.x = f2bf(a0c.x); lo.y = f2bf(a0c.y); lo.z = f2bf(a0c.z); lo.w = f2bf(a0c.w);
    hi.x = f2bf(a1c.x); hi.y = f2bf(a1c.y); hi.z = f2bf(a1c.z); hi.w = f2bf(a1c.w);
    *(ushort4*)(&As[0][ldr][ldk]) = lo;
    *(ushort4*)(&As[0][ldr][ldk + 4]) = hi;
    *(uint4*)(&Bs[0][ldr][ldk]) = bvc;
  }
  __syncthreads();

#pragma unroll
  for (int kb = 0; kb < 8; kb++) {
    const int cur = kb & 1;
    if (kb < 7) {                         // stage kb+1 into the other buffer
      ushort4 lo, hi;
      lo.x = f2bf(a0n.x); lo.y = f2bf(a0n.y); lo.z = f2bf(a0n.z); lo.w = f2bf(a0n.w);
      hi.x = f2bf(a1n.x); hi.y = f2bf(a1n.y); hi.z = f2bf(a1n.z); hi.w = f2bf(a1n.w);
      *(ushort4*)(&As[cur ^ 1][ldr][ldk]) = lo;
      *(ushort4*)(&As[cur ^ 1][ldr][ldk + 4]) = hi;
      *(uint4*)(&Bs[cur ^ 1][ldr][ldk]) = bvn;
      if (kb < 6) {                       // issue kb+2
        const int k2 = (kb + 2) * 32;
        if (aok) { a0n = *(const float4*)(ap + k2); a1n = *(const float4*)(ap + k2 + 4); }
        if (bok) bvn = *(const uint4*)(bp + k2);
      }
    }
    short8 af[2], bfr[2];
    for (int i = 0; i < 2; i++)
      af[i] = *(const short8*)(&As[cur][wm * 32 + i * 16 + l16][quad * 8]);
    for (int j = 0; j < 2; j++)
      bfr[j] = *(const short8*)(&Bs[cur][wn * 32 + j * 16 + l16][quad * 8]);
    for (int i = 0; i < 2; i++)
      for (int j = 0; j < 2; j++)
        acc[i][j] = __builtin_amdgcn_mfma_f32_16x16x32_bf16(af[i], bfr[j], acc[i][j], 0, 0, 0);
    __syncthreads();                      // ONE barrier per K-step
  }

  for (int i = 0; i < 2; i++)
    for (int j = 0; j < 2; j++) {
      int colg = bn * 64 + wn * 32 + j * 16 + l16;
      if (colg >= N) continue;
      float bsv = bias[colg];
      int row0 = bm * 64 + wm * 32 + i * 16 + quad * 4;
      for (int r = 0; r < 4; r++) {
        int rg = row0 + r;
        if (rg >= MTOT) continue;
        float v = acc[i][j][r] + bsv;
        if (is2) {
          logits[(size_t)rg * 288 + colg] = v;
        } else {
          int b = (rg >= LQn) ? 1 : 0;
          int p = rg - b * LQn;
          value16[((size_t)(b * 8 + (colg >> 5)) * LQn + p) * 32 + (colg & 31)] = f2bf(v);
        }
      }
    }
}

// ---------------- GEMM3: dbuf-LDS single-barrier, 2-deep prefetch, NT stores ----------
// 1D grid 348*4, XCD-chunk swizzled, bm = lb/4.
__global__ __launch_bounds__(256) void gemm_a16(
    const unsigned short* __restrict__ A,   // (M,256) bf16
    const unsigned short* __restrict__ Bt,  // (256,256) bf16 N-major
    const float* __restrict__ bias,
    float* __restrict__ C) {                // (M,256) fp32
  __shared__ unsigned short As[2][64][40];
  __shared__ unsigned short Bs[2][64][40];

  const int lb = xcd_swz(blockIdx.x, gridDim.x);
  const int bm = lb >> 2;
  const int bn = lb & 3;

  const int t = threadIdx.x;
  const int wave = t >> 6, lane = t & 63;
  const int wm = wave >> 1, wn = wave & 1;
  const int quad = lane >> 4, l16 = lane & 15;

  const int ldr = t >> 2;
  const int ldk = (t & 3) * 8;
  const int arow = bm * 64 + ldr;
  const int brow = bn * 64 + ldr;
  const bool aok = arow < MTOT;
  const unsigned short* ap = A + (size_t)arow * 256 + ldk;
  const unsigned short* bp = Bt + (size_t)brow * 256 + ldk;

  f32x4 acc[2][2];
  for (int i = 0; i < 2; i++)
    for (int j = 0; j < 2; j++) acc[i][j] = (f32x4){0.f, 0.f, 0.f, 0.f};

  uint4 avc = {0u,0u,0u,0u}, avn = avc, bvc, bvn;
  if (aok) { avc = *(const uint4*)(ap); avn = *(const uint4*)(ap + 32); }
  bvc = *(const uint4*)(bp);
  bvn = *(const uint4*)(bp + 32);

  *(uint4*)(&As[0][ldr][ldk]) = avc;
  *(uint4*)(&Bs[0][ldr][ldk]) = bvc;
  __syncthreads();

#pragma unroll
  for (int kb = 0; kb < 8; kb++) {
    const int cur = kb & 1;
    if (kb < 7) {
      *(uint4*)(&As[cur ^ 1][ldr][ldk]) = avn;
      *(uint4*)(&Bs[cur ^ 1][ldr][ldk]) = bvn;
      if (kb < 6) {
        const int k2 = (kb + 2) * 32;
        if (aok) avn = *(const uint4*)(ap + k2);
        bvn = *(const uint4*)(bp + k2);
      }
    }
    short8 af[2], bfr[2];
    for (int i = 0; i < 2; i++)
      af[i] = *(const short8*)(&As[cur][wm * 32 + i * 16 + l16][quad * 8]);
    for (int j = 0; j < 2; j++)
      bfr[j] = *(const short8*)(&Bs[cur][wn * 32 + j * 16 + l16][quad * 8]);
    for (int i = 0; i < 2; i++)
      for (int j = 0; j < 2; j++)
        acc[i][j] = __builtin_amdgcn_mfma_f32_16x16x32_bf16(af[i], bfr[j], acc[i][j], 0, 0, 0);
    __syncthreads();
  }

  for (int i = 0; i < 2; i++)
    for (int j = 0; j < 2; j++) {
      int colg = bn * 64 + wn * 32 + j * 16 + l16;
      float bsv = bias[colg];
      int row0 = bm * 64 + wm * 32 + i * 16 + quad * 4;
      for (int r = 0; r < 4; r++) {
        int rg = row0 + r;
        if (rg < MTOT)
          __builtin_nontemporal_store(acc[i][j][r] + bsv, &C[(size_t)rg * 256 + colg]);
      }
    }
}

// ---------------- sampling + softmax + weighted sum (R12/R14-exact, ~43.5us) --------
// head-major value16, cached logits, XCD swizzle, simple phase-C loop, no
// launch_bounds cap, no logit stash (R15: +3KB LDS dropped 8->7 blocks/CU).
__global__ __launch_bounds__(256) void msda_sample4(
    const unsigned short* __restrict__ value16,  // [b][h][pix][32] bf16
    const float* __restrict__ logits,            // (M,288)
    const float* __restrict__ refp,              // (M,3,2) (y,x)
    unsigned short* __restrict__ sampled) {      // (M,256) bf16
  __shared__ float          tw[8][96][4];   // 12.3 KB
  __shared__ unsigned short ti[8][96][4];   // 6.1 KB
  __shared__ float hmx[8][8], hrd[8][8];
  __shared__ float rfs[8][6];

  const int t = threadIdx.x;
  const int nbid = xcd_swz(blockIdx.x, gridDim.x);
  const int qbase = nbid * 8;

  if (t < 48) {
    int q = t / 6;
    if (qbase + q < MTOT) rfs[q][t - q * 6] = refp[(size_t)qbase * 6 + t];
  }
  if (t >= 64 && t < 128) {
    int tt = t - 64;
    int q = tt >> 3, h = tt & 7;
    int bq = qbase + q;
    if (bq < MTOT) {
      const float* lrow = logits + (size_t)bq * 288 + 192 + h * 12;
      float mx = -1e30f;
#pragma unroll
      for (int i = 0; i < 12; i++) mx = fmaxf(mx, lrow[i]);
      float den = 0.f;
#pragma unroll
      for (int i = 0; i < 12; i++) den += __expf(lrow[i] - mx);
      hmx[q][h] = mx;
      hrd[q][h] = 1.0f / den;
    }
  }
  __syncthreads();

  {
    const int Hs[3] = {92, 46, 23};
    const int Ss[3] = {0, 8464, 10580};
#pragma unroll
    for (int r = 0; r < 3; r++) {
      const int task = t + r * 256;
      const int q = task / 96, s = task - q * 96;
      const int bq = qbase + q;
      if (bq < MTOT) {
        const int h = s / 12, pl = s - h * 12;
        const int l = pl >> 2;
        const int H = Hs[l], W = Hs[l], S = Ss[l];
        const float* lrow = logits + (size_t)bq * 288;
        const float aw = __expf(lrow[192 + s] - hmx[q][h]) * hrd[q][h];
        const float offy = lrow[2 * s], offx = lrow[2 * s + 1];
        const float x = rfs[q][l * 2 + 1] * W + offx - 0.5f;
        const float y = rfs[q][l * 2 + 0] * H + offy - 0.5f;
        const float xf = floorf(x), yf = floorf(y);
        const int x0 = (int)xf, y0 = (int)yf;
        const float lx = x - xf, ly = y - yf;
        const bool xv0 = (x0 >= 0) & (x0 < W), xv1 = (x0 + 1 >= 0) & (x0 + 1 < W);
        const bool yv0 = (y0 >= 0) & (y0 < H), yv1 = (y0 + 1 >= 0) & (y0 + 1 < H);
        const int xc0 = min(max(x0, 0), W - 1), xc1 = min(max(x0 + 1, 0), W - 1);
        const int yc0 = min(max(y0, 0), H - 1), yc1 = min(max(y0 + 1, 0), H - 1);
        const int slot = pl * 8 + h;
        ti[q][slot][0] = (unsigned short)(S + yc0 * W + xc0);
        ti[q][slot][1] = (unsigned short)(S + yc0 * W + xc1);
        ti[q][slot][2] = (unsigned short)(S + yc1 * W + xc0);
        ti[q][slot][3] = (unsigned short)(S + yc1 * W + xc1);
        tw[q][slot][0] = (yv0 & xv0) ? aw * (1.f - ly) * (1.f - lx) : 0.f;
        tw[q][slot][1] = (yv0 & xv1) ? aw * (1.f - ly) * lx : 0.f;
        tw[q][slot][2] = (yv1 & xv0) ? aw * ly * (1.f - lx) : 0.f;
        tw[q][slot][3] = (yv1 & xv1) ? aw * ly * lx : 0.f;
      }
    }
  }
  __syncthreads();

  {
    const int w = t >> 6, lane = t & 63;
    const int q = w * 2 + (lane >> 5);
    const int h = (lane >> 2) & 7, cg = lane & 3;
    const int bq = qbase + q;
    const bool qv = bq < MTOT;
    const int bqc = qv ? bq : 0;
    const char* __restrict__ vb =
        (const char*)value16 + (size_t)(bqc / LQn) * ((size_t)LQn * 512);
    const unsigned laneoff = (unsigned)h * (LQn * 64u) + (unsigned)cg * 16u;

    float a0 = 0.f, a1 = 0.f, a2 = 0.f, a3 = 0.f;
    float a4 = 0.f, a5 = 0.f, a6 = 0.f, a7 = 0.f;
#pragma unroll
    for (int p = 0; p < 12; p++) {
      const int slot = p * 8 + h;
      const ushort4 tiv = *(const ushort4*)(&ti[q][slot][0]);
      const f32x4 wv = *(const f32x4*)(&tw[q][slot][0]);
#pragma unroll
      for (int k = 0; k < 4; k++) {
        const unsigned pix =
            (k == 0) ? tiv.x : (k == 1) ? tiv.y : (k == 2) ? tiv.z : tiv.w;
        const float wgt = wv[k];
        const uint4 u = *(const uint4*)(vb + ((pix << 6) + laneoff));
        a0 += wgt * __uint_as_float(u.x << 16);
        a1 += wgt * __uint_as_float(u.x & 0xffff0000u);
        a2 += wgt * __uint_as_float(u.y << 16);
        a3 += wgt * __uint_as_float(u.y & 0xffff0000u);
        a4 += wgt * __uint_as_float(u.z << 16);
        a5 += wgt * __uint_as_float(u.z & 0xffff0000u);
        a6 += wgt * __uint_as_float(u.w << 16);
        a7 += wgt * __uint_as_float(u.w & 0xffff0000u);
      }
    }
    if (qv) {
      uint4 o;
      o.x = (unsigned)f2bf(a0) | ((unsigned)f2bf(a1) << 16);
      o.y = (unsigned)f2bf(a2) | ((unsigned)f2bf(a3) << 16);
      o.z = (unsigned)f2bf(a4) | ((unsigned)f2bf(a5) << 16);
      o.w = (unsigned)f2bf(a6) | ((unsigned)f2bf(a7) << 16);
      *(uint4*)(sampled + (size_t)bq * 256 + h * 32 + cg * 8) = o;
    }
  }
}

// ---------------- host launch ----------------
extern "C" void kernel_launch(void* const* d_in, const int* in_sizes, int n_in,
                              void* d_out, int out_size, void* d_ws, size_t ws_size,
                              hipStream_t stream) {
  const float* query      = (const float*)d_in[0];
  const float* refp       = (const float*)d_in[1];
  const float* value_flat = (const float*)d_in[2];
  const float* W_val      = (const float*)d_in[3];
  const float* b_val      = (const float*)d_in[4];
  const float* W_off      = (const float*)d_in[5];
  const float* b_off      = (const float*)d_in[6];
  const float* W_attn     = (const float*)d_in[7];
  const float* b_attn     = (const float*)d_in[8];
  const float* W_out      = (const float*)d_in[9];
  const float* b_out      = (const float*)d_in[10];

  char* w = (char*)d_ws;
  size_t o = 0;
  auto carve = [&](size_t bytes) -> void* {
    void* p = (void*)(w + o);
    o += (bytes + 255) & ~(size_t)255;
    return p;
  };
  unsigned short* Wval_t  = (unsigned short*)carve(256 * 256 * 2);
  unsigned short* Wcat_t  = (unsigned short*)carve(288 * 256 * 2);
  unsigned short* Wout_t  = (unsigned short*)carve(256 * 256 * 2);
  float*          bcat    = (float*)carve(288 * 4);
  unsigned short* value16 = (unsigned short*)carve((size_t)MTOT * 256 * 2);
  float*          logits  = (float*)carve((size_t)MTOT * 288 * 4);
  unsigned short* samp_bf = (unsigned short*)carve((size_t)MTOT * 256 * 2);

  prep_weights<<<288, 256, 0, stream>>>(W_val, W_off, W_attn, W_out, b_off, b_attn,
                                        Wval_t, Wcat_t, Wout_t, bcat);

  const int mg = (MTOT + 63) / 64;               // 348
  gemm_fused12<<<mg * 9, 256, 0, stream>>>(value_flat, query, Wval_t, Wcat_t,
                                           b_val, bcat, value16, logits);

  const int sgrid = (MTOT + 7) / 8;              // 2778
  msda_sample4<<<sgrid, 256, 0, stream>>>(value16, logits, refp, samp_bf);

  gemm_a16<<<mg * 4, 256, 0, stream>>>(samp_bf, Wout_t, b_out, (float*)d_out);
}

// Round 17
// 184.575 us; speedup vs baseline: 1.0525x; 1.0525x over previous
//
#include <hip/hip_runtime.h>

// MSDeformAttn: B=2, LQ=LV=11109, D=256, NH=8, HD=32, NL=3, NP=4
// shapes: (92,92),(46,46),(23,23); starts: 0, 8464, 10580
#define LQn   11109
#define MTOT  22218   // B * LQ

typedef __attribute__((ext_vector_type(8))) short short8;
typedef __attribute__((ext_vector_type(4))) float f32x4;

__device__ __forceinline__ unsigned short f2bf(float f) {
  union { float f; unsigned int u; } v; v.f = f;
  unsigned int r = v.u + 0x7fffu + ((v.u >> 16) & 1u);  // RNE
  return (unsigned short)(r >> 16);
}

// bijective XCD chunk swizzle: consecutive logical blocks -> same XCD
__device__ __forceinline__ int xcd_swz(int bid, int nwg) {
  const int xcd = bid & 7, pos = bid >> 3;
  const int q = nwg >> 3, r = nwg & 7;
  return (xcd < r ? xcd * (q + 1) : r * (q + 1) + (xcd - r) * q) + pos;
}

// ---------------- weight prep: transpose to (N x K) bf16, concat biases ----------------
__global__ __launch_bounds__(256) void prep_weights(
    const float* __restrict__ Wval, const float* __restrict__ Woff,
    const float* __restrict__ Wattn, const float* __restrict__ Wout,
    const float* __restrict__ boff, const float* __restrict__ battn,
    unsigned short* __restrict__ Wval_t, unsigned short* __restrict__ Wcat_t,
    unsigned short* __restrict__ Wout_t, float* __restrict__ bcat) {
  int i = blockIdx.x * 256 + threadIdx.x;   // grid = 288 blocks -> i < 73728
  int n = i >> 8, k = i & 255;              // Wt[n][k] = W[k][n]
  if (n < 256) {
    Wval_t[i] = f2bf(Wval[k * 256 + n]);
    Wout_t[i] = f2bf(Wout[k * 256 + n]);
  }
  float src = (n < 192) ? Woff[k * 192 + n] : Wattn[k * 96 + (n - 192)];
  Wcat_t[i] = f2bf(src);
  if (i < 288) bcat[i] = (i < 192) ? boff[i] : battn[i - 192];
}

// ---------------- fused GEMM1+GEMM2: 512 threads, BM=128 x BN=64, dbuf LDS
// (30.7KB -> 4 blocks/CU x 8 waves = 32 waves/CU vs 16 before), ONE barrier
// per K-step, 2-deep register prefetch. 1D grid 174*9, XCD-chunk swizzled.
__global__ __launch_bounds__(512) void gemm_fused12(
    const float* __restrict__ Aval,           // (M,256) fp32
    const float* __restrict__ Aq,             // (M,256) fp32
    const unsigned short* __restrict__ Bval,  // (256,256) bf16 N-major
    const unsigned short* __restrict__ Bcat,  // (288,256) bf16 N-major
    const float* __restrict__ bval, const float* __restrict__ bcat,
    unsigned short* __restrict__ value16,     // [b][h][pix][32] bf16
    float* __restrict__ logits) {             // (M,288) fp32
  __shared__ unsigned short As[2][128][40];   // 20.5 KB
  __shared__ unsigned short Bs[2][64][40];    // 10.2 KB

  const int lb = xcd_swz(blockIdx.x, gridDim.x);
  const int bm = lb / 9;
  int bn = lb - bm * 9;
  const bool is2 = bn >= 4;
  if (is2) bn -= 4;
  const float* __restrict__ A = is2 ? Aq : Aval;
  const unsigned short* __restrict__ Bt = is2 ? Bcat : Bval;
  const float* __restrict__ bias = is2 ? bcat : bval;
  const int N = is2 ? 288 : 256;

  const int t = threadIdx.x;
  const int wave = t >> 6, lane = t & 63;     // 8 waves
  const int wm = wave >> 1, wn = wave & 1;    // 4 x 2 wave grid
  const int quad = lane >> 4, l16 = lane & 15;

  const int ldr = t >> 2;                     // 0..127 (A staging row)
  const int ldk = (t & 3) * 8;
  const int arow = bm * 128 + ldr;
  const bool aok = arow < MTOT;
  const float* ap = A + (size_t)arow * 256 + ldk;

  const bool bstage = t < 256;                // threads 0..255 stage B (64 rows)
  const int brow = bn * 64 + (t >> 2);        // valid only when bstage
  const bool bok = bstage && (brow < N);
  const unsigned short* bp = Bt + (size_t)brow * 256 + ldk;

  f32x4 acc[2][2];
  for (int i = 0; i < 2; i++)
    for (int j = 0; j < 2; j++) acc[i][j] = (f32x4){0.f, 0.f, 0.f, 0.f};

  // 2-deep prefetch: c = staged this iter, n = staged next iter
  float4 a0c = {0.f,0.f,0.f,0.f}, a1c = a0c, a0n = a0c, a1n = a0c;
  uint4 bvc = {0u,0u,0u,0u}, bvn = bvc;
  if (aok) { a0c = *(const float4*)(ap);      a1c = *(const float4*)(ap + 4);
             a0n = *(const float4*)(ap + 32); a1n = *(const float4*)(ap + 36); }
  if (bok) { bvc = *(const uint4*)(bp);       bvn = *(const uint4*)(bp + 32); }

  {
    ushort4 lo, hi;
    lo.x = f2bf(a0c.x); lo.y = f2bf(a0c.y); lo.z = f2bf(a0c.z); lo.w = f2bf(a0c.w);
    hi.x = f2bf(a1c.x); hi.y = f2bf(a1c.y); hi.z = f2bf(a1c.z); hi.w = f2bf(a1c.w);
    *(ushort4*)(&As[0][ldr][ldk]) = lo;
    *(ushort4*)(&As[0][ldr][ldk + 4]) = hi;
    if (bstage) *(uint4*)(&Bs[0][t >> 2][ldk]) = bvc;
  }
  __syncthreads();

#pragma unroll
  for (int kb = 0; kb < 8; kb++) {
    const int cur = kb & 1;
    if (kb < 7) {                         // stage kb+1 into the other buffer
      ushort4 lo, hi;
      lo.x = f2bf(a0n.x); lo.y = f2bf(a0n.y); lo.z = f2bf(a0n.z); lo.w = f2bf(a0n.w);
      hi.x = f2bf(a1n.x); hi.y = f2bf(a1n.y); hi.z = f2bf(a1n.z); hi.w = f2bf(a1n.w);
      *(ushort4*)(&As[cur ^ 1][ldr][ldk]) = lo;
      *(ushort4*)(&As[cur ^ 1][ldr][ldk + 4]) = hi;
      if (bstage) *(uint4*)(&Bs[cur ^ 1][t >> 2][ldk]) = bvn;
      if (kb < 6) {                       // issue kb+2
        const int k2 = (kb + 2) * 32;
        if (aok) { a0n = *(const float4*)(ap + k2); a1n = *(const float4*)(ap + k2 + 4); }
        if (bok) bvn = *(const uint4*)(bp + k2);
      }
    }
    short8 af[2], bfr[2];
    for (int i = 0; i < 2; i++)
      af[i] = *(const short8*)(&As[cur][wm * 32 + i * 16 + l16][quad * 8]);
    for (int j = 0; j < 2; j++)
      bfr[j] = *(const short8*)(&Bs[cur][wn * 32 + j * 16 + l16][quad * 8]);
    for (int i = 0; i < 2; i++)
      for (int j = 0; j < 2; j++)
        acc[i][j] = __builtin_amdgcn_mfma_f32_16x16x32_bf16(af[i], bfr[j], acc[i][j], 0, 0, 0);
    __syncthreads();                      // ONE barrier per K-step
  }

  for (int i = 0; i < 2; i++)
    for (int j = 0; j < 2; j++) {
      int colg = bn * 64 + wn * 32 + j * 16 + l16;
      if (colg >= N) continue;
      float bsv = bias[colg];
      int row0 = bm * 128 + wm * 32 + i * 16 + quad * 4;
      for (int r = 0; r < 4; r++) {
        int rg = row0 + r;
        if (rg >= MTOT) continue;
        float v = acc[i][j][r] + bsv;
        if (is2) {
          logits[(size_t)rg * 288 + colg] = v;
        } else {
          int b = (rg >= LQn) ? 1 : 0;
          int p = rg - b * LQn;
          value16[((size_t)(b * 8 + (colg >> 5)) * LQn + p) * 32 + (colg & 31)] = f2bf(v);
        }
      }
    }
}

// ---------------- GEMM3: 512 threads, BM=128, dbuf single-barrier, NT stores ----------
// 1D grid 174*4, XCD-chunk swizzled, bm = lb/4.
__global__ __launch_bounds__(512) void gemm_a16(
    const unsigned short* __restrict__ A,   // (M,256) bf16
    const unsigned short* __restrict__ Bt,  // (256,256) bf16 N-major
    const float* __restrict__ bias,
    float* __restrict__ C) {                // (M,256) fp32
  __shared__ unsigned short As[2][128][40];
  __shared__ unsigned short Bs[2][64][40];

  const int lb = xcd_swz(blockIdx.x, gridDim.x);
  const int bm = lb >> 2;
  const int bn = lb & 3;

  const int t = threadIdx.x;
  const int wave = t >> 6, lane = t & 63;
  const int wm = wave >> 1, wn = wave & 1;
  const int quad = lane >> 4, l16 = lane & 15;

  const int ldr = t >> 2;                 // 0..127
  const int ldk = (t & 3) * 8;
  const int arow = bm * 128 + ldr;
  const bool aok = arow < MTOT;
  const unsigned short* ap = A + (size_t)arow * 256 + ldk;

  const bool bstage = t < 256;
  const int brow = bn * 64 + (t >> 2);    // < 256 when bstage
  const unsigned short* bp = Bt + (size_t)brow * 256 + ldk;

  f32x4 acc[2][2];
  for (int i = 0; i < 2; i++)
    for (int j = 0; j < 2; j++) acc[i][j] = (f32x4){0.f, 0.f, 0.f, 0.f};

  uint4 avc = {0u,0u,0u,0u}, avn = avc, bvc = avc, bvn = avc;
  if (aok) { avc = *(const uint4*)(ap); avn = *(const uint4*)(ap + 32); }
  if (bstage) { bvc = *(const uint4*)(bp); bvn = *(const uint4*)(bp + 32); }

  *(uint4*)(&As[0][ldr][ldk]) = avc;
  if (bstage) *(uint4*)(&Bs[0][t >> 2][ldk]) = bvc;
  __syncthreads();

#pragma unroll
  for (int kb = 0; kb < 8; kb++) {
    const int cur = kb & 1;
    if (kb < 7) {
      *(uint4*)(&As[cur ^ 1][ldr][ldk]) = avn;
      if (bstage) *(uint4*)(&Bs[cur ^ 1][t >> 2][ldk]) = bvn;
      if (kb < 6) {
        const int k2 = (kb + 2) * 32;
        if (aok) avn = *(const uint4*)(ap + k2);
        if (bstage) bvn = *(const uint4*)(bp + k2);
      }
    }
    short8 af[2], bfr[2];
    for (int i = 0; i < 2; i++)
      af[i] = *(const short8*)(&As[cur][wm * 32 + i * 16 + l16][quad * 8]);
    for (int j = 0; j < 2; j++)
      bfr[j] = *(const short8*)(&Bs[cur][wn * 32 + j * 16 + l16][quad * 8]);
    for (int i = 0; i < 2; i++)
      for (int j = 0; j < 2; j++)
        acc[i][j] = __builtin_amdgcn_mfma_f32_16x16x32_bf16(af[i], bfr[j], acc[i][j], 0, 0, 0);
    __syncthreads();
  }

  for (int i = 0; i < 2; i++)
    for (int j = 0; j < 2; j++) {
      int colg = bn * 64 + wn * 32 + j * 16 + l16;
      float bsv = bias[colg];
      int row0 = bm * 128 + wm * 32 + i * 16 + quad * 4;
      for (int r = 0; r < 4; r++) {
        int rg = row0 + r;
        if (rg < MTOT)
          __builtin_nontemporal_store(acc[i][j][r] + bsv, &C[(size_t)rg * 256 + colg]);
      }
    }
}

// ---------------- sampling + softmax + weighted sum (R12/R14-exact, ~43.5us) --------
__global__ __launch_bounds__(256) void msda_sample4(
    const unsigned short* __restrict__ value16,  // [b][h][pix][32] bf16
    const float* __restrict__ logits,            // (M,288)
    const float* __restrict__ refp,              // (M,3,2) (y,x)
    unsigned short* __restrict__ sampled) {      // (M,256) bf16
  __shared__ float          tw[8][96][4];   // 12.3 KB
  __shared__ unsigned short ti[8][96][4];   // 6.1 KB
  __shared__ float hmx[8][8], hrd[8][8];
  __shared__ float rfs[8][6];

  const int t = threadIdx.x;
  const int nbid = xcd_swz(blockIdx.x, gridDim.x);
  const int qbase = nbid * 8;

  if (t < 48) {
    int q = t / 6;
    if (qbase + q < MTOT) rfs[q][t - q * 6] = refp[(size_t)qbase * 6 + t];
  }
  if (t >= 64 && t < 128) {
    int tt = t - 64;
    int q = tt >> 3, h = tt & 7;
    int bq = qbase + q;
    if (bq < MTOT) {
      const float* lrow = logits + (size_t)bq * 288 + 192 + h * 12;
      float mx = -1e30f;
#pragma unroll
      for (int i = 0; i < 12; i++) mx = fmaxf(mx, lrow[i]);
      float den = 0.f;
#pragma unroll
      for (int i = 0; i < 12; i++) den += __expf(lrow[i] - mx);
      hmx[q][h] = mx;
      hrd[q][h] = 1.0f / den;
    }
  }
  __syncthreads();

  {
    const int Hs[3] = {92, 46, 23};
    const int Ss[3] = {0, 8464, 10580};
#pragma unroll
    for (int r = 0; r < 3; r++) {
      const int task = t + r * 256;
      const int q = task / 96, s = task - q * 96;
      const int bq = qbase + q;
      if (bq < MTOT) {
        const int h = s / 12, pl = s - h * 12;
        const int l = pl >> 2;
        const int H = Hs[l], W = Hs[l], S = Ss[l];
        const float* lrow = logits + (size_t)bq * 288;
        const float aw = __expf(lrow[192 + s] - hmx[q][h]) * hrd[q][h];
        const float offy = lrow[2 * s], offx = lrow[2 * s + 1];
        const float x = rfs[q][l * 2 + 1] * W + offx - 0.5f;
        const float y = rfs[q][l * 2 + 0] * H + offy - 0.5f;
        const float xf = floorf(x), yf = floorf(y);
        const int x0 = (int)xf, y0 = (int)yf;
        const float lx = x - xf, ly = y - yf;
        const bool xv0 = (x0 >= 0) & (x0 < W), xv1 = (x0 + 1 >= 0) & (x0 + 1 < W);
        const bool yv0 = (y0 >= 0) & (y0 < H), yv1 = (y0 + 1 >= 0) & (y0 + 1 < H);
        const int xc0 = min(max(x0, 0), W - 1), xc1 = min(max(x0 + 1, 0), W - 1);
        const int yc0 = min(max(y0, 0), H - 1), yc1 = min(max(y0 + 1, 0), H - 1);
        const int slot = pl * 8 + h;
        ti[q][slot][0] = (unsigned short)(S + yc0 * W + xc0);
        ti[q][slot][1] = (unsigned short)(S + yc0 * W + xc1);
        ti[q][slot][2] = (unsigned short)(S + yc1 * W + xc0);
        ti[q][slot][3] = (unsigned short)(S + yc1 * W + xc1);
        tw[q][slot][0] = (yv0 & xv0) ? aw * (1.f - ly) * (1.f - lx) : 0.f;
        tw[q][slot][1] = (yv0 & xv1) ? aw * (1.f - ly) * lx : 0.f;
        tw[q][slot][2] = (yv1 & xv0) ? aw * ly * (1.f - lx) : 0.f;
        tw[q][slot][3] = (yv1 & xv1) ? aw * ly * lx : 0.f;
      }
    }
  }
  __syncthreads();

  {
    const int w = t >> 6, lane = t & 63;
    const int q = w * 2 + (lane >> 5);
    const int h = (lane >> 2) & 7, cg = lane & 3;
    const int bq = qbase + q;
    const bool qv = bq < MTOT;
    const int bqc = qv ? bq : 0;
    const char* __restrict__ vb =
        (const char*)value16 + (size_t)(bqc / LQn) * ((size_t)LQn * 512);
    const unsigned laneoff = (unsigned)h * (LQn * 64u) + (unsigned)cg * 16u;

    float a0 = 0.f, a1 = 0.f, a2 = 0.f, a3 = 0.f;
    float a4 = 0.f, a5 = 0.f, a6 = 0.f, a7 = 0.f;
#pragma unroll
    for (int p = 0; p < 12; p++) {
      const int slot = p * 8 + h;
      const ushort4 tiv = *(const ushort4*)(&ti[q][slot][0]);
      const f32x4 wv = *(const f32x4*)(&tw[q][slot][0]);
#pragma unroll
      for (int k = 0; k < 4; k++) {
        const unsigned pix =
            (k == 0) ? tiv.x : (k == 1) ? tiv.y : (k == 2) ? tiv.z : tiv.w;
        const float wgt = wv[k];
        const uint4 u = *(const uint4*)(vb + ((pix << 6) + laneoff));
        a0 += wgt * __uint_as_float(u.x << 16);
        a1 += wgt * __uint_as_float(u.x & 0xffff0000u);
        a2 += wgt * __uint_as_float(u.y << 16);
        a3 += wgt * __uint_as_float(u.y & 0xffff0000u);
        a4 += wgt * __uint_as_float(u.z << 16);
        a5 += wgt * __uint_as_float(u.z & 0xffff0000u);
        a6 += wgt * __uint_as_float(u.w << 16);
        a7 += wgt * __uint_as_float(u.w & 0xffff0000u);
      }
    }
    if (qv) {
      uint4 o;
      o.x = (unsigned)f2bf(a0) | ((unsigned)f2bf(a1) << 16);
      o.y = (unsigned)f2bf(a2) | ((unsigned)f2bf(a3) << 16);
      o.z = (unsigned)f2bf(a4) | ((unsigned)f2bf(a5) << 16);
      o.w = (unsigned)f2bf(a6) | ((unsigned)f2bf(a7) << 16);
      *(uint4*)(sampled + (size_t)bq * 256 + h * 32 + cg * 8) = o;
    }
  }
}

// ---------------- host launch ----------------
extern "C" void kernel_launch(void* const* d_in, const int* in_sizes, int n_in,
                              void* d_out, int out_size, void* d_ws, size_t ws_size,
                              hipStream_t stream) {
  const float* query      = (const float*)d_in[0];
  const float* refp       = (const float*)d_in[1];
  const float* value_flat = (const float*)d_in[2];
  const float* W_val      = (const float*)d_in[3];
  const float* b_val      = (const float*)d_in[4];
  const float* W_off      = (const float*)d_in[5];
  const float* b_off      = (const float*)d_in[6];
  const float* W_attn     = (const float*)d_in[7];
  const float* b_attn     = (const float*)d_in[8];
  const float* W_out      = (const float*)d_in[9];
  const float* b_out      = (const float*)d_in[10];

  char* w = (char*)d_ws;
  size_t o = 0;
  auto carve = [&](size_t bytes) -> void* {
    void* p = (void*)(w + o);
    o += (bytes + 255) & ~(size_t)255;
    return p;
  };
  unsigned short* Wval_t  = (unsigned short*)carve(256 * 256 * 2);
  unsigned short* Wcat_t  = (unsigned short*)carve(288 * 256 * 2);
  unsigned short* Wout_t  = (unsigned short*)carve(256 * 256 * 2);
  float*          bcat    = (float*)carve(288 * 4);
  unsigned short* value16 = (unsigned short*)carve((size_t)MTOT * 256 * 2);
  float*          logits  = (float*)carve((size_t)MTOT * 288 * 4);
  unsigned short* samp_bf = (unsigned short*)carve((size_t)MTOT * 256 * 2);

  prep_weights<<<288, 256, 0, stream>>>(W_val, W_off, W_attn, W_out, b_off, b_attn,
                                        Wval_t, Wcat_t, Wout_t, bcat);

  const int mg128 = (MTOT + 127) / 128;          // 174
  gemm_fused12<<<mg128 * 9, 512, 0, stream>>>(value_flat, query, Wval_t, Wcat_t,
                                              b_val, bcat, value16, logits);

  const int sgrid = (MTOT + 7) / 8;              // 2778
  msda_sample4<<<sgrid, 256, 0, stream>>>(value16, logits, refp, samp_bf);

  gemm_a16<<<mg128 * 4, 512, 0, stream>>>(samp_bf, Wout_t, b_out, (float*)d_out);
}